// Round 1
// 584.841 us; speedup vs baseline: 1.1907x; 1.1907x over previous
//
#include <hip/hip_runtime.h>
#include <hip/hip_bf16.h>
#include <stdint.h>

// JinaEmbeddingsV3SelfOutput, algebraically folded:
//   h2 = hs @ Weff_t^T + beff_t,   Weff_t = W@W + 0.25*B_t@(A_t@W)  [per task]
//   beff_t = W@b + b + 0.25*B_t@(A_t@b)
//   out = LN(h2 + input)
// One big GEMM (32768x1024x1024, bf16 MFMA, m97-structure global_load_lds)
// instead of two; LoRA + bias folded into per-task weights on device.
#define D_HID 1024
#define M_TOT 32768
#define LN_EPS 1e-5f

typedef __bf16 bf16x8 __attribute__((ext_vector_type(8)));
typedef float f32x4 __attribute__((ext_vector_type(4)));
typedef unsigned short u16;
typedef u16 u16x8 __attribute__((ext_vector_type(8)));
typedef u16 u16x4v __attribute__((ext_vector_type(4)));

__device__ __forceinline__ float bf2f(u16 x) {
  union { unsigned int u; float f; } c; c.u = ((unsigned int)x) << 16; return c.f;
}
__device__ __forceinline__ u16 f2bf(float f) {
  union { __bf16 h; u16 u; } c; c.h = (__bf16)f; return c.u;  // RNE
}
__device__ __forceinline__ u16x8 cvt8(const float* g) {
  float4 f0 = *(const float4*)g;
  float4 f1 = *(const float4*)(g + 4);
  u16x8 v;
  v[0] = f2bf(f0.x); v[1] = f2bf(f0.y); v[2] = f2bf(f0.z); v[3] = f2bf(f0.w);
  v[4] = f2bf(f1.x); v[5] = f2bf(f1.y); v[6] = f2bf(f1.z); v[7] = f2bf(f1.w);
  return v;
}
// Async global->LDS, 16B/lane. lds base must be wave-uniform; lane i lands at
// base + i*16 (guide m97/m104). Global src is per-lane.
__device__ __forceinline__ void gld16(const u16* g, u16* lds_wave_base) {
  __builtin_amdgcn_global_load_lds(
      (__attribute__((address_space(1))) unsigned int*)g,
      (__attribute__((address_space(3))) unsigned int*)lds_wave_base, 16, 0, 0);
}

// ---------------- hs fp32 -> bf16 (one pass) ----------------
__global__ __launch_bounds__(256) void cvt_hs(const float* __restrict__ in,
                                              u16* __restrict__ out) {
  const int n8 = M_TOT * D_HID / 8;
  int i = blockIdx.x * 256 + threadIdx.x;
  const int stride = gridDim.x * 256;
  for (; i < n8; i += stride)
    *(u16x8*)(out + (size_t)i * 8) = cvt8(in + (size_t)i * 8);
}

// ---------------- W -> split bf16 (hi+lo) and its transpose ----------------
__global__ __launch_bounds__(256) void prep_w(const float* __restrict__ W,
    u16* __restrict__ hi, u16* __restrict__ lo,
    u16* __restrict__ hiT, u16* __restrict__ loT) {
  __shared__ float tile[32][33];
  const int bj = blockIdx.x, bi = blockIdx.y;
  const int tx = threadIdx.x & 31, ty = threadIdx.x >> 5;
#pragma unroll
  for (int r0 = 0; r0 < 32; r0 += 8) {
    const int r = r0 + ty;
    const size_t o = (size_t)(bi * 32 + r) * D_HID + bj * 32 + tx;
    const float v = W[o];
    tile[r][tx] = v;
    const u16 h = f2bf(v);
    hi[o] = h; lo[o] = f2bf(v - bf2f(h));
  }
  __syncthreads();
#pragma unroll
  for (int r0 = 0; r0 < 32; r0 += 8) {
    const int r = r0 + ty;
    const float v = tile[tx][r];  // WT[bj*32+r][bi*32+tx] = W[bi*32+tx][bj*32+r]
    const size_t o = (size_t)(bj * 32 + r) * D_HID + bi * 32 + tx;
    const u16 h = f2bf(v);
    hiT[o] = h; loT[o] = f2bf(v - bf2f(h));
  }
}

// ---------------- Wc = W@W, split-bf16 (hi*hi + lo*hi + hi*lo), fp32 out ----
__global__ __launch_bounds__(256, 1) void gemm_wc(
    const u16* __restrict__ Ah, const u16* __restrict__ Al,
    const u16* __restrict__ Bh, const u16* __restrict__ Bl,
    float* __restrict__ C) {
  __shared__ __align__(16) u16 sAh[128 * 32], sAl[128 * 32];
  __shared__ __align__(16) u16 sBh[128 * 32], sBl[128 * 32];
  const int tid = threadIdx.x, wave = tid >> 6, lane = tid & 63;
  const int bx = blockIdx.x, by = blockIdx.y;
  const int srow = tid >> 2, scol = (tid & 3) * 8;
  size_t aOff = (size_t)(by * 128 + srow) * D_HID + scol;
  size_t bOff = (size_t)(bx * 128 + srow) * D_HID + scol;
  const int wb = wave * 512;
  const int wm = wave >> 1, wn = wave & 1;
  const int mrow = lane & 15, quad = lane >> 4;
  const int fA = (wm * 64 + mrow) * 32 + quad * 8;
  const int fB = (wn * 64 + mrow) * 32 + quad * 8;
  f32x4 acc[4][4];
#pragma unroll
  for (int i = 0; i < 4; ++i)
#pragma unroll
    for (int j = 0; j < 4; ++j) acc[i][j] = (f32x4){0.f, 0.f, 0.f, 0.f};

  for (int k0 = 0; k0 < D_HID; k0 += 32) {
    __syncthreads();
    gld16(Ah + aOff, sAh + wb); gld16(Ah + aOff + 64 * D_HID, sAh + wb + 2048);
    gld16(Al + aOff, sAl + wb); gld16(Al + aOff + 64 * D_HID, sAl + wb + 2048);
    gld16(Bh + bOff, sBh + wb); gld16(Bh + bOff + 64 * D_HID, sBh + wb + 2048);
    gld16(Bl + bOff, sBl + wb); gld16(Bl + bOff + 64 * D_HID, sBl + wb + 2048);
    aOff += 32; bOff += 32;
    __syncthreads();
    bf16x8 ah[4], al4[4], bh[4], bl4[4];
#pragma unroll
    for (int m = 0; m < 4; ++m) {
      ah[m]  = *(const bf16x8*)(sAh + fA + m * 512);
      al4[m] = *(const bf16x8*)(sAl + fA + m * 512);
    }
#pragma unroll
    for (int n = 0; n < 4; ++n) {
      bh[n]  = *(const bf16x8*)(sBh + fB + n * 512);
      bl4[n] = *(const bf16x8*)(sBl + fB + n * 512);
    }
#pragma unroll
    for (int m = 0; m < 4; ++m)
#pragma unroll
      for (int n = 0; n < 4; ++n) {
        acc[m][n] = __builtin_amdgcn_mfma_f32_16x16x32_bf16(ah[m],  bh[n],  acc[m][n], 0, 0, 0);
        acc[m][n] = __builtin_amdgcn_mfma_f32_16x16x32_bf16(al4[m], bh[n],  acc[m][n], 0, 0, 0);
        acc[m][n] = __builtin_amdgcn_mfma_f32_16x16x32_bf16(ah[m],  bl4[n], acc[m][n], 0, 0, 0);
      }
  }
  const int mBase = by * 128 + wm * 64, nBase = bx * 128 + wn * 64;
#pragma unroll
  for (int m = 0; m < 4; ++m)
#pragma unroll
    for (int n = 0; n < 4; ++n) {
      const int nn = nBase + n * 16 + mrow;
#pragma unroll
      for (int r = 0; r < 4; ++r) {
        const int mm = mBase + m * 16 + quad * 4 + r;
        C[(size_t)mm * D_HID + nn] = acc[m][n][r];
      }
    }
}

// ---------------- A2[t,r,:] = A_t[r,:]@W  and  c[t,r] = A_t[r,:]·b (fp32) ----
__global__ __launch_bounds__(256) void a2c_kernel(
    const float* __restrict__ lA, const float* __restrict__ W,
    const float* __restrict__ bvec, float* __restrict__ A2,
    float* __restrict__ cvec) {
  const int tr = blockIdx.x;  // t*4 + r, 0..19
  const int tid = threadIdx.x;
  const float* arow = lA + (size_t)tr * D_HID;
  float4 acc = {0.f, 0.f, 0.f, 0.f};
#pragma unroll 8
  for (int d = 0; d < D_HID; ++d) {
    const float a = arow[d];
    const float4 w = *(const float4*)(W + (size_t)d * D_HID + tid * 4);
    acc.x += a * w.x; acc.y += a * w.y; acc.z += a * w.z; acc.w += a * w.w;
  }
  *(float4*)(A2 + (size_t)tr * D_HID + tid * 4) = acc;
  const float4 av = *(const float4*)(arow + tid * 4);
  const float4 bv = *(const float4*)(bvec + tid * 4);
  float p = av.x * bv.x + av.y * bv.y + av.z * bv.z + av.w * bv.w;
#pragma unroll
  for (int off = 32; off > 0; off >>= 1) p += __shfl_down(p, off);
  __shared__ float red[4];
  if ((tid & 63) == 0) red[tid >> 6] = p;
  __syncthreads();
  if (tid == 0) cvec[tr] = red[0] + red[1] + red[2] + red[3];
}

// ---------------- Weff_t = bf16(Wc + 0.25*B_t@A2_t); beff_t fp32 ----------------
__global__ __launch_bounds__(256) void weff_beff(
    const float* __restrict__ Wc, const float* __restrict__ A2,
    const float* __restrict__ cvec, const float* __restrict__ lB,
    const float* __restrict__ W, const float* __restrict__ bvec,
    u16* __restrict__ Weff, float* __restrict__ beff) {
  const int n = blockIdx.x, t = blockIdx.y, tid = threadIdx.x;
  float br[4];
#pragma unroll
  for (int r = 0; r < 4; ++r) br[r] = lB[(size_t)t * 4096 + n * 4 + r];
  float4 v = *(const float4*)(Wc + (size_t)n * D_HID + tid * 4);
#pragma unroll
  for (int r = 0; r < 4; ++r) {
    const float4 a2 = *(const float4*)(A2 + (size_t)(t * 4 + r) * D_HID + tid * 4);
    const float s = 0.25f * br[r];
    v.x += s * a2.x; v.y += s * a2.y; v.z += s * a2.z; v.w += s * a2.w;
  }
  u16x4v o; o[0] = f2bf(v.x); o[1] = f2bf(v.y); o[2] = f2bf(v.z); o[3] = f2bf(v.w);
  *(u16x4v*)(Weff + (size_t)t * 1048576 + (size_t)n * D_HID + tid * 4) = o;
  // beff[t][n] = W[n,:]·b + b[n] + 0.25 * sum_r B_t[n,r]*c[t,r]
  const float4 wr = *(const float4*)(W + (size_t)n * D_HID + tid * 4);
  const float4 bb = *(const float4*)(bvec + tid * 4);
  float p = wr.x * bb.x + wr.y * bb.y + wr.z * bb.z + wr.w * bb.w;
#pragma unroll
  for (int off = 32; off > 0; off >>= 1) p += __shfl_down(p, off);
  __shared__ float red[4];
  if ((tid & 63) == 0) red[tid >> 6] = p;
  __syncthreads();
  if (tid == 0) {
    float e = 0.f;
#pragma unroll
    for (int r = 0; r < 4; ++r) e += br[r] * cvec[t * 4 + r];
    beff[t * D_HID + n] = red[0] + red[1] + red[2] + red[3] + bvec[n] + 0.25f * e;
  }
}

// ---------------- main GEMM: out = hs_bf @ Weff[task]^T + beff + resid ----------
// m97 structure: 128x128 tile, BK=32, 4 waves (2x2 of 64x64), global_load_lds w=16.
__global__ __launch_bounds__(256, 2) void gemm_main(
    const u16* __restrict__ A, const u16* __restrict__ Wf,
    const float* __restrict__ beff, const float* __restrict__ resid,
    const int* __restrict__ mask, float* __restrict__ out) {
  __shared__ __align__(16) u16 sA[128 * 32], sB[128 * 32];
  const int tid = threadIdx.x, wave = tid >> 6, lane = tid & 63;
  const int bx = blockIdx.x, by = blockIdx.y;
  const int task = mask[by >> 4];  // 128-row tile never crosses a batch (S=2048)
  const u16* Bt = Wf + (size_t)task * (D_HID * D_HID);
  const int srow = tid >> 2, scol = (tid & 3) * 8;
  size_t aOff = (size_t)(by * 128 + srow) * D_HID + scol;
  size_t bOff = (size_t)(bx * 128 + srow) * D_HID + scol;
  const int wb = wave * 512;  // wave-uniform LDS base (u16 units)
  const int wm = wave >> 1, wn = wave & 1;
  const int mrow = lane & 15, quad = lane >> 4;
  const int fA = (wm * 64 + mrow) * 32 + quad * 8;
  const int fB = (wn * 64 + mrow) * 32 + quad * 8;
  f32x4 acc[4][4];
#pragma unroll
  for (int i = 0; i < 4; ++i)
#pragma unroll
    for (int j = 0; j < 4; ++j) acc[i][j] = (f32x4){0.f, 0.f, 0.f, 0.f};

  for (int k0 = 0; k0 < D_HID; k0 += 32) {
    __syncthreads();  // prior iteration's LDS reads done
    gld16(A + aOff,              sA + wb);
    gld16(A + aOff + 64 * D_HID, sA + wb + 2048);
    gld16(Bt + bOff,             sB + wb);
    gld16(Bt + bOff + 64 * D_HID, sB + wb + 2048);
    aOff += 32; bOff += 32;
    __syncthreads();  // vmcnt(0) drain -> tile visible
    bf16x8 af[4], bfr[4];
#pragma unroll
    for (int m = 0; m < 4; ++m) af[m]  = *(const bf16x8*)(sA + fA + m * 512);
#pragma unroll
    for (int n = 0; n < 4; ++n) bfr[n] = *(const bf16x8*)(sB + fB + n * 512);
#pragma unroll
    for (int m = 0; m < 4; ++m)
#pragma unroll
      for (int n = 0; n < 4; ++n)
        acc[m][n] = __builtin_amdgcn_mfma_f32_16x16x32_bf16(af[m], bfr[n], acc[m][n], 0, 0, 0);
  }

  // epilogue: + beff[task] + resid, fp32 store. C/D: col=lane&15, row=quad*4+r.
  const float* bb = beff + task * D_HID;
  const size_t mBase = (size_t)by * 128 + wm * 64;
  const int nBase = bx * 128 + wn * 64;
#pragma unroll
  for (int mf = 0; mf < 4; ++mf)
#pragma unroll
    for (int nf = 0; nf < 4; ++nf) {
      const int n = nBase + nf * 16 + mrow;
      const float bval = bb[n];
#pragma unroll
      for (int r = 0; r < 4; ++r) {
        const size_t m = mBase + mf * 16 + quad * 4 + r;
        out[m * D_HID + n] = acc[mf][nf][r] + bval + resid[m * D_HID + n];
      }
    }
}

// ---------------- in-place row LayerNorm ----------------
__global__ __launch_bounds__(256) void ln_kernel(float* __restrict__ io,
                                                 const float* __restrict__ gamma,
                                                 const float* __restrict__ beta) {
  const int row = blockIdx.x;
  const int tid = threadIdx.x;
  float* p = io + (size_t)row * D_HID + tid * 4;
  float4 v = *(const float4*)p;
  float s = v.x + v.y + v.z + v.w;
  float q = v.x * v.x + v.y * v.y + v.z * v.z + v.w * v.w;
#pragma unroll
  for (int off = 32; off > 0; off >>= 1) {
    s += __shfl_down(s, off);
    q += __shfl_down(q, off);
  }
  __shared__ float red[8];
  const int wave = tid >> 6, lane = tid & 63;
  if (lane == 0) { red[wave] = s; red[4 + wave] = q; }
  __syncthreads();
  const float tot  = red[0] + red[1] + red[2] + red[3];
  const float totq = red[4] + red[5] + red[6] + red[7];
  const float mu  = tot * (1.f / (float)D_HID);
  const float var = totq * (1.f / (float)D_HID) - mu * mu;
  const float inv = rsqrtf(var + LN_EPS);
  float4 g  = *(const float4*)(gamma + tid * 4);
  float4 bb = *(const float4*)(beta + tid * 4);
  float4 o;
  o.x = (v.x - mu) * inv * g.x + bb.x;
  o.y = (v.y - mu) * inv * g.y + bb.y;
  o.z = (v.z - mu) * inv * g.z + bb.z;
  o.w = (v.w - mu) * inv * g.w + bb.w;
  *(float4*)p = o;
}

extern "C" void kernel_launch(void* const* d_in, const int* in_sizes, int n_in,
                              void* d_out, int out_size, void* d_ws, size_t ws_size,
                              hipStream_t stream) {
  const float* hs    = (const float*)d_in[0];  // [16,2048,1024] fp32
  const float* inp   = (const float*)d_in[1];  // [16,2048,1024] fp32
  const float* W     = (const float*)d_in[2];  // [1024,1024] fp32
  const float* b     = (const float*)d_in[3];  // [1024]
  const float* lA    = (const float*)d_in[4];  // [5,4,1024]
  const float* lB    = (const float*)d_in[5];  // [5,1024,4]
  const float* gamma = (const float*)d_in[6];
  const float* beta  = (const float*)d_in[7];
  const int*   mask  = (const int*)d_in[8];    // [16]
  float* out = (float*)d_out;

  // Workspace layout (78.1 MiB total):
  //  [0, 64M)        hs_bf  bf16 hs
  //  [64M, +4M)      Wc     fp32 W@W
  //  [+4M, +10M)     Weff   bf16 [5][1024][1024]; its first 8 MB double as the
  //                  split-W temps (Whi/Wlo/WhiT/WloT) which die before Weff is
  //                  written (stream-ordered: prep_w -> gemm_wc -> weff_beff).
  //  tail            A2 (80K), cvec, beff (20K)
  char* wsb = (char*)d_ws;
  u16*   hs_bf = (u16*)wsb;                     // 67,108,864 B
  float* Wc    = (float*)(wsb + 67108864);      //  4,194,304 B
  u16*   weff  = (u16*)(wsb + 71303168);        // 10,485,760 B
  u16*   Whi   = weff;
  u16*   Wlo   = weff + 1048576;
  u16*   WhiT  = weff + 2097152;
  u16*   WloT  = weff + 3145728;
  float* A2    = (float*)(wsb + 81788928);      // 81,920 B
  float* cvec  = (float*)(wsb + 81870848);      // 80 B
  float* beff  = (float*)(wsb + 81871360);      // 20,480 B

  cvt_hs<<<2048, 256, 0, stream>>>(hs, hs_bf);
  prep_w<<<dim3(32, 32), 256, 0, stream>>>(W, Whi, Wlo, WhiT, WloT);
  gemm_wc<<<dim3(8, 8), 256, 0, stream>>>(Whi, Wlo, WhiT, WloT, Wc);
  a2c_kernel<<<20, 256, 0, stream>>>(lA, W, b, A2, cvec);
  weff_beff<<<dim3(1024, 5), 256, 0, stream>>>(Wc, A2, cvec, lB, W, b, weff, beff);
  gemm_main<<<dim3(8, 256), 256, 0, stream>>>(hs_bf, weff, beff, inp, mask, out);
  ln_kernel<<<M_TOT, 256, 0, stream>>>(out, gamma, beta);
}

// Round 2
// 524.262 us; speedup vs baseline: 1.3283x; 1.1156x over previous
//
#include <hip/hip_runtime.h>
#include <hip/hip_bf16.h>
#include <stdint.h>

// JinaEmbeddingsV3SelfOutput, algebraically folded:
//   h2 = hs @ Weff_t^T + beff_t,   Weff_t = W@W + 0.25*B_t@(A_t@W)  [per task]
//   beff_t = W@b + b + 0.25*B_t@(A_t@b)
//   out = LN(h2 + input)
// Launches: S1{cvt_hs, prep_w} -> S2{gemm_wc, a2c} -> S3{weff+beff}
//           -> gemm_main (2-phase dbuf, LDS XOR swizzle, XCD clustering) -> ln.
#define D_HID 1024
#define M_TOT 32768
#define LN_EPS 1e-5f

typedef __bf16 bf16x8 __attribute__((ext_vector_type(8)));
typedef float f32x4 __attribute__((ext_vector_type(4)));
typedef unsigned short u16;
typedef u16 u16x8 __attribute__((ext_vector_type(8)));
typedef u16 u16x4v __attribute__((ext_vector_type(4)));

__device__ __forceinline__ float bf2f(u16 x) {
  union { unsigned int u; float f; } c; c.u = ((unsigned int)x) << 16; return c.f;
}
__device__ __forceinline__ u16 f2bf(float f) {
  union { __bf16 h; u16 u; } c; c.h = (__bf16)f; return c.u;  // RNE
}
__device__ __forceinline__ u16x8 cvt8(const float* g) {
  float4 f0 = *(const float4*)g;
  float4 f1 = *(const float4*)(g + 4);
  u16x8 v;
  v[0] = f2bf(f0.x); v[1] = f2bf(f0.y); v[2] = f2bf(f0.z); v[3] = f2bf(f0.w);
  v[4] = f2bf(f1.x); v[5] = f2bf(f1.y); v[6] = f2bf(f1.z); v[7] = f2bf(f1.w);
  return v;
}
// Async global->LDS, 16B/lane. LDS dest is wave-uniform base + lane*16.
__device__ __forceinline__ void gld16(const u16* g, u16* lds_wave_base) {
  __builtin_amdgcn_global_load_lds(
      (__attribute__((address_space(1))) unsigned int*)g,
      (__attribute__((address_space(3))) unsigned int*)lds_wave_base, 16, 0, 0);
}

// ---------------- S1: hs->bf16 (blocks 0..2047) + W split/transpose (2048..3071) ----
__global__ __launch_bounds__(256) void s1_prep(
    const float* __restrict__ hs, u16* __restrict__ hs_bf,
    const float* __restrict__ W, u16* __restrict__ hi, u16* __restrict__ lo,
    u16* __restrict__ hiT, u16* __restrict__ loT) {
  __shared__ float tile[32][33];
  const int bid = blockIdx.x, tid = threadIdx.x;
  if (bid < 2048) {
    int i = bid * 256 + tid;          // 2048*256*8 == 32768*1024/8 exactly
#pragma unroll
    for (int it = 0; it < 8; ++it, i += 2048 * 256)
      *(u16x8*)(hs_bf + (size_t)i * 8) = cvt8(hs + (size_t)i * 8);
    return;
  }
  const int rb = bid - 2048;
  const int bj = rb & 31, bi = rb >> 5;
  const int tx = tid & 31, ty = tid >> 5;
#pragma unroll
  for (int r0 = 0; r0 < 32; r0 += 8) {
    const int r = r0 + ty;
    const size_t o = (size_t)(bi * 32 + r) * D_HID + bj * 32 + tx;
    const float v = W[o];
    tile[r][tx] = v;
    const u16 h = f2bf(v);
    hi[o] = h; lo[o] = f2bf(v - bf2f(h));
  }
  __syncthreads();
#pragma unroll
  for (int r0 = 0; r0 < 32; r0 += 8) {
    const int r = r0 + ty;
    const float v = tile[tx][r];  // WT[bj*32+r][bi*32+tx]
    const size_t o = (size_t)(bj * 32 + r) * D_HID + bi * 32 + tx;
    const u16 h = f2bf(v);
    hiT[o] = h; loT[o] = f2bf(v - bf2f(h));
  }
}

// ---------------- S2: Wc = W@W (blocks 0..63, split-bf16) + A2 = lA@W (rest) ----
// a2c role reconstructs fp32 W^T rows from hiT+loT (hi+lo sums back to ~fp32).
__global__ __launch_bounds__(256, 1) void s2_wc_a2c(
    const u16* __restrict__ Ah, const u16* __restrict__ Al,
    const u16* __restrict__ Bh, const u16* __restrict__ Bl,
    const float* __restrict__ lA, float* __restrict__ C,
    float* __restrict__ A2) {
  __shared__ __align__(16) u16 sAh[128 * 32], sAl[128 * 32];
  __shared__ __align__(16) u16 sBh[128 * 32], sBl[128 * 32];
  const int bid = blockIdx.x, tid = threadIdx.x, wave = tid >> 6, lane = tid & 63;
  if (bid >= 64) {
    // one wave per output element of A2[20][1024]
    const int job = (bid - 64) * 4 + wave;   // 0..20479
    const int tr = job >> 10, e = job & 1023;
    const u16* ht = Bh + (size_t)e * D_HID + lane * 16;  // Bh/Bl hold W^T
    const u16* lt = Bl + (size_t)e * D_HID + lane * 16;
    const float* ar = lA + (size_t)tr * D_HID + lane * 16;
    u16x8 h0 = *(const u16x8*)ht, h1 = *(const u16x8*)(ht + 8);
    u16x8 l0 = *(const u16x8*)lt, l1 = *(const u16x8*)(lt + 8);
    float acc = 0.f;
#pragma unroll
    for (int j = 0; j < 8; ++j) {
      acc += ar[j]     * (bf2f(h0[j]) + bf2f(l0[j]));
      acc += ar[8 + j] * (bf2f(h1[j]) + bf2f(l1[j]));
    }
#pragma unroll
    for (int m = 1; m < 64; m <<= 1) acc += __shfl_xor(acc, m);
    if (lane == 0) A2[(size_t)tr * D_HID + e] = acc;
    return;
  }
  // wc role: 128x128 tile split-bf16 GEMM, grid 8x8
  const int bx = bid & 7, by = bid >> 3;
  const int srow = tid >> 2, scol = (tid & 3) * 8;
  size_t aOff = (size_t)(by * 128 + srow) * D_HID + scol;
  size_t bOff = (size_t)(bx * 128 + srow) * D_HID + scol;
  const int wb = wave * 512;
  const int wm = wave >> 1, wn = wave & 1;
  const int mrow = lane & 15, quad = lane >> 4;
  const int fA = (wm * 64 + mrow) * 32 + quad * 8;
  const int fB = (wn * 64 + mrow) * 32 + quad * 8;
  f32x4 acc[4][4];
#pragma unroll
  for (int i = 0; i < 4; ++i)
#pragma unroll
    for (int j = 0; j < 4; ++j) acc[i][j] = (f32x4){0.f, 0.f, 0.f, 0.f};
  for (int k0 = 0; k0 < D_HID; k0 += 32) {
    __syncthreads();
    gld16(Ah + aOff, sAh + wb); gld16(Ah + aOff + 64 * D_HID, sAh + wb + 2048);
    gld16(Al + aOff, sAl + wb); gld16(Al + aOff + 64 * D_HID, sAl + wb + 2048);
    gld16(Bh + bOff, sBh + wb); gld16(Bh + bOff + 64 * D_HID, sBh + wb + 2048);
    gld16(Bl + bOff, sBl + wb); gld16(Bl + bOff + 64 * D_HID, sBl + wb + 2048);
    aOff += 32; bOff += 32;
    __syncthreads();
    bf16x8 ah[4], al4[4], bh[4], bl4[4];
#pragma unroll
    for (int m = 0; m < 4; ++m) {
      ah[m]  = *(const bf16x8*)(sAh + fA + m * 512);
      al4[m] = *(const bf16x8*)(sAl + fA + m * 512);
    }
#pragma unroll
    for (int n = 0; n < 4; ++n) {
      bh[n]  = *(const bf16x8*)(sBh + fB + n * 512);
      bl4[n] = *(const bf16x8*)(sBl + fB + n * 512);
    }
#pragma unroll
    for (int m = 0; m < 4; ++m)
#pragma unroll
      for (int n = 0; n < 4; ++n) {
        acc[m][n] = __builtin_amdgcn_mfma_f32_16x16x32_bf16(ah[m],  bh[n],  acc[m][n], 0, 0, 0);
        acc[m][n] = __builtin_amdgcn_mfma_f32_16x16x32_bf16(al4[m], bh[n],  acc[m][n], 0, 0, 0);
        acc[m][n] = __builtin_amdgcn_mfma_f32_16x16x32_bf16(ah[m],  bl4[n], acc[m][n], 0, 0, 0);
      }
  }
  const int mBase = by * 128 + wm * 64, nBase = bx * 128 + wn * 64;
#pragma unroll
  for (int m = 0; m < 4; ++m)
#pragma unroll
    for (int n = 0; n < 4; ++n) {
      const int nn = nBase + n * 16 + mrow;
#pragma unroll
      for (int r = 0; r < 4; ++r)
        C[(size_t)(mBase + m * 16 + quad * 4 + r) * D_HID + nn] = acc[m][n][r];
    }
}

// ---------------- S3: Weff_t = bf16(Wc + 0.25*B_t@A2_t); beff_t (cvec inline) ----
__global__ __launch_bounds__(256) void weff_beff(
    const float* __restrict__ Wc, const float* __restrict__ A2,
    const float* __restrict__ lB, const float* __restrict__ lA,
    const float* __restrict__ W, const float* __restrict__ bvec,
    u16* __restrict__ Weff, float* __restrict__ beff) {
  const int n = blockIdx.x, t = blockIdx.y, tid = threadIdx.x;
  const int wave = tid >> 6, lane = tid & 63;
  float br[4];
#pragma unroll
  for (int r = 0; r < 4; ++r) br[r] = lB[(size_t)t * 4096 + n * 4 + r];
  float4 v = *(const float4*)(Wc + (size_t)n * D_HID + tid * 4);
#pragma unroll
  for (int r = 0; r < 4; ++r) {
    const float4 a2 = *(const float4*)(A2 + (size_t)(t * 4 + r) * D_HID + tid * 4);
    const float s = 0.25f * br[r];
    v.x += s * a2.x; v.y += s * a2.y; v.z += s * a2.z; v.w += s * a2.w;
  }
  u16x4v o; o[0] = f2bf(v.x); o[1] = f2bf(v.y); o[2] = f2bf(v.z); o[3] = f2bf(v.w);
  *(u16x4v*)(Weff + (size_t)t * 1048576 + (size_t)n * D_HID + tid * 4) = o;
  // beff[t][n] = W[n,:]·b + b[n] + 0.25 * sum_r B_t[n,r] * (lA[t,r,:]·b)
  const float4 bb = *(const float4*)(bvec + tid * 4);
  float p[5];
  {
    const float4 wr = *(const float4*)(W + (size_t)n * D_HID + tid * 4);
    p[0] = wr.x * bb.x + wr.y * bb.y + wr.z * bb.z + wr.w * bb.w;
  }
#pragma unroll
  for (int r = 0; r < 4; ++r) {
    const float4 ar = *(const float4*)(lA + (size_t)(t * 4 + r) * D_HID + tid * 4);
    p[1 + r] = ar.x * bb.x + ar.y * bb.y + ar.z * bb.z + ar.w * bb.w;
  }
#pragma unroll
  for (int m = 1; m < 64; m <<= 1)
#pragma unroll
    for (int j = 0; j < 5; ++j) p[j] += __shfl_xor(p[j], m);
  __shared__ float red[4][5];
  if (lane == 0)
#pragma unroll
    for (int j = 0; j < 5; ++j) red[wave][j] = p[j];
  __syncthreads();
  if (tid == 0) {
    float P = 0.f, Cr[4] = {0.f, 0.f, 0.f, 0.f};
#pragma unroll
    for (int w = 0; w < 4; ++w) {
      P += red[w][0];
#pragma unroll
      for (int r = 0; r < 4; ++r) Cr[r] += red[w][1 + r];
    }
    float e = 0.f;
#pragma unroll
    for (int r = 0; r < 4; ++r) e += br[r] * Cr[r];
    beff[t * D_HID + n] = P + bvec[n] + 0.25f * e;
  }
}

// ---------------- main GEMM: out = hs_bf @ Weff[task]^T + beff + resid ----------
// 128x128 tile, BK=32, 4 waves. 2-phase LDS double-buffer (T3 minimum recipe),
// 2-bit XOR bank swizzle (pre-swizzled global src + swizzled ds_read, rule #21),
// XCD-clustered block remap (8 N-blocks of one M-tile contiguous on one XCD).
__global__ __launch_bounds__(256, 3) void gemm_main(
    const u16* __restrict__ A, const u16* __restrict__ Wf,
    const float* __restrict__ beff, const float* __restrict__ resid,
    const int* __restrict__ mask, float* __restrict__ out) {
  __shared__ __align__(16) u16 sA[2][128 * 32], sB[2][128 * 32];
  const int tid = threadIdx.x, wave = tid >> 6, lane = tid & 63;
  const int L = blockIdx.x + 8 * blockIdx.y;     // linear dispatch id
  const int by = (L & 7) * 32 + (L >> 6);        // XCD = L%8 hosts 32 M-tiles
  const int bx = (L >> 3) & 7;                   // 8 consecutive L share by
  const int task = mask[by >> 4];
  const u16* Bt = Wf + (size_t)task * (D_HID * D_HID);
  const int srow = tid >> 2;
  const int scol = ((tid & 3) ^ (srow & 3)) * 8;  // swizzled k-chunk (bijective: XOR within 64B row)
  size_t aOff = (size_t)(by * 128 + srow) * D_HID + scol;
  size_t bOff = (size_t)(bx * 128 + srow) * D_HID + scol;
  const int wb = wave * 512;
  const int wm = wave >> 1, wn = wave & 1;
  const int mrow = lane & 15, quad = lane >> 4;
  const int fA = (wm * 64 + mrow) * 32 + ((quad ^ (mrow & 3)) * 8);
  const int fB = (wn * 64 + mrow) * 32 + ((quad ^ (mrow & 3)) * 8);
  f32x4 acc[4][4];
#pragma unroll
  for (int i = 0; i < 4; ++i)
#pragma unroll
    for (int j = 0; j < 4; ++j) acc[i][j] = (f32x4){0.f, 0.f, 0.f, 0.f};

  auto stage = [&](int buf) {
    gld16(A + aOff,               &sA[buf][wb]);
    gld16(A + aOff + 64 * D_HID,  &sA[buf][wb + 2048]);
    gld16(Bt + bOff,              &sB[buf][wb]);
    gld16(Bt + bOff + 64 * D_HID, &sB[buf][wb + 2048]);
    aOff += 32; bOff += 32;
  };

  stage(0);
  __syncthreads();  // drains vmcnt(0): tile 0 resident
  int cur = 0;
  for (int t = 0; t < 32; ++t) {
    if (t < 31) stage(cur ^ 1);  // next-tile loads fly under this tile's MFMA
    bf16x8 af[4], bfr[4];
#pragma unroll
    for (int m = 0; m < 4; ++m) af[m]  = *(const bf16x8*)(&sA[cur][fA + m * 512]);
#pragma unroll
    for (int n = 0; n < 4; ++n) bfr[n] = *(const bf16x8*)(&sB[cur][fB + n * 512]);
#pragma unroll
    for (int m = 0; m < 4; ++m)
#pragma unroll
      for (int n = 0; n < 4; ++n)
        acc[m][n] = __builtin_amdgcn_mfma_f32_16x16x32_bf16(af[m], bfr[n], acc[m][n], 0, 0, 0);
    __syncthreads();  // reads of buf[cur] done AND buf[cur^1] staged (vmcnt 0)
    cur ^= 1;
  }

  // epilogue: + beff[task] + resid, fp32 store. C/D: col=lane&15, row=quad*4+r.
  const float* bb = beff + task * D_HID;
  const size_t mBase = (size_t)by * 128 + wm * 64;
  const int nBase = bx * 128 + wn * 64;
#pragma unroll
  for (int mf = 0; mf < 4; ++mf)
#pragma unroll
    for (int nf = 0; nf < 4; ++nf) {
      const int n = nBase + nf * 16 + mrow;
      const float bval = bb[n];
#pragma unroll
      for (int r = 0; r < 4; ++r) {
        const size_t m = mBase + mf * 16 + quad * 4 + r;
        out[m * D_HID + n] = acc[mf][nf][r] + bval + resid[m * D_HID + n];
      }
    }
}

// ---------------- in-place LN, one wave per row (no LDS, no sync) ----------------
__global__ __launch_bounds__(256) void ln4(float* __restrict__ io,
                                           const float* __restrict__ gamma,
                                           const float* __restrict__ beta) {
  const int row = blockIdx.x * 4 + (threadIdx.x >> 6);
  const int lane = threadIdx.x & 63;
  float* p = io + (size_t)row * D_HID + lane * 16;
  float4 v0 = ((const float4*)p)[0], v1 = ((const float4*)p)[1];
  float4 v2 = ((const float4*)p)[2], v3 = ((const float4*)p)[3];
  float s = v0.x + v0.y + v0.z + v0.w + v1.x + v1.y + v1.z + v1.w
          + v2.x + v2.y + v2.z + v2.w + v3.x + v3.y + v3.z + v3.w;
  float q = v0.x*v0.x + v0.y*v0.y + v0.z*v0.z + v0.w*v0.w
          + v1.x*v1.x + v1.y*v1.y + v1.z*v1.z + v1.w*v1.w
          + v2.x*v2.x + v2.y*v2.y + v2.z*v2.z + v2.w*v2.w
          + v3.x*v3.x + v3.y*v3.y + v3.z*v3.z + v3.w*v3.w;
#pragma unroll
  for (int m = 1; m < 64; m <<= 1) { s += __shfl_xor(s, m); q += __shfl_xor(q, m); }
  const float mu  = s * (1.f / (float)D_HID);
  const float var = q * (1.f / (float)D_HID) - mu * mu;
  const float inv = rsqrtf(var + LN_EPS);
  const float4* gp = (const float4*)(gamma + lane * 16);
  const float4* bp = (const float4*)(beta + lane * 16);
  float4 g, bbv, o;
#define LNW(k, vk) \
  g = gp[k]; bbv = bp[k]; \
  o.x = (vk.x - mu) * inv * g.x + bbv.x; o.y = (vk.y - mu) * inv * g.y + bbv.y; \
  o.z = (vk.z - mu) * inv * g.z + bbv.z; o.w = (vk.w - mu) * inv * g.w + bbv.w; \
  ((float4*)p)[k] = o;
  LNW(0, v0) LNW(1, v1) LNW(2, v2) LNW(3, v3)
#undef LNW
}

extern "C" void kernel_launch(void* const* d_in, const int* in_sizes, int n_in,
                              void* d_out, int out_size, void* d_ws, size_t ws_size,
                              hipStream_t stream) {
  const float* hs    = (const float*)d_in[0];  // [16,2048,1024] fp32
  const float* inp   = (const float*)d_in[1];  // [16,2048,1024] fp32
  const float* W     = (const float*)d_in[2];  // [1024,1024] fp32
  const float* b     = (const float*)d_in[3];  // [1024]
  const float* lA    = (const float*)d_in[4];  // [5,4,1024]
  const float* lB    = (const float*)d_in[5];  // [5,1024,4]
  const float* gamma = (const float*)d_in[6];
  const float* beta  = (const float*)d_in[7];
  const int*   mask  = (const int*)d_in[8];    // [16]
  float* out = (float*)d_out;

  // Workspace (81.9 MiB, same as last round):
  //  [0,64M)      hs_bf bf16
  //  [64M,+4M)    Wc fp32
  //  [+4M,+10M)   Weff bf16 [5][1024][1024]; first 8MB double as Whi/Wlo/WhiT/WloT
  //               (live S1->S2 only; Weff written in S3, stream-ordered).
  //  tail         A2 (80K), beff (20K)
  char* wsb = (char*)d_ws;
  u16*   hs_bf = (u16*)wsb;
  float* Wc    = (float*)(wsb + 67108864);
  u16*   weff  = (u16*)(wsb + 71303168);
  u16*   Whi   = weff;
  u16*   Wlo   = weff + 1048576;
  u16*   WhiT  = weff + 2097152;
  u16*   WloT  = weff + 3145728;
  float* A2    = (float*)(wsb + 81788928);
  float* beff  = (float*)(wsb + 81871360);

  s1_prep<<<3072, 256, 0, stream>>>(hs, hs_bf, W, Whi, Wlo, WhiT, WloT);
  s2_wc_a2c<<<64 + 5120, 256, 0, stream>>>(Whi, Wlo, WhiT, WloT, lA, Wc, A2);
  weff_beff<<<dim3(1024, 5), 256, 0, stream>>>(Wc, A2, lB, lA, W, b, weff, beff);
  gemm_main<<<dim3(8, 256), 256, 0, stream>>>(hs_bf, weff, beff, inp, mask, out);
  ln4<<<M_TOT / 4, 256, 0, stream>>>(out, gamma, beta);
}